// Round 1
// 1082.749 us; speedup vs baseline: 1.0715x; 1.0715x over previous
//
#include <hip/hip_runtime.h>

// Problem constants (from reference): Q=512 states, S=64 symbols, B=64, T=256.
#define QN 512
#define SN 64
#define BN 64
#define TN 256
#define GS 4   // row-split: blocks per batch (grid = GS*BN = 256 blocks -> 256 CUs)

typedef unsigned long long ull;

// ---- int8 dot4 (v_dot4_i32_i8) with software fallback ----
#if defined(__has_builtin)
#if __has_builtin(__builtin_amdgcn_sdot4)
#define SDOT4(a, b, c) __builtin_amdgcn_sdot4((a), (b), (c), false)
#endif
#endif
#ifndef SDOT4
static __device__ __forceinline__ int sdot4_sw(int a, int b, int c) {
    c += (int)(signed char)(a)       * (int)(signed char)(b);
    c += (int)(signed char)(a >> 8)  * (int)(signed char)(b >> 8);
    c += (int)(signed char)(a >> 16) * (int)(signed char)(b >> 16);
    c += (int)(signed char)(a >> 24) * (int)(signed char)(b >> 24);
    return c;
}
#define SDOT4(a, b, c) sdot4_sw((a), (b), (c))
#endif

static __device__ __forceinline__ float wave_sum(float v) {
    #pragma unroll
    for (int o = 32; o > 0; o >>= 1) v += __shfl_xor(v, o, 64);
    return v;
}
static __device__ __forceinline__ float wave_max(float v) {
    #pragma unroll
    for (int o = 32; o > 0; o >>= 1) v = fmaxf(v, __shfl_xor(v, o, 64));
    return v;
}

// Barrier with LDS-only drain: waits lgkmcnt(0) but leaves global loads in
// flight (vmcnt untouched) so cross-step register prefetch survives the
// barrier. imm encoding (gfx9/CDNA): vm[3:0]=0xF, exp[6:4]=7, lgkm[11:8]=0,
// vm[15:14]=3 -> 0xC07F.
static __device__ __forceinline__ void barrier_lds(void) {
    __builtin_amdgcn_s_waitcnt(0xC07F);
    __builtin_amdgcn_s_barrier();
}

// Tagged-word exchange through the LLC (agent scope => sc0|sc1, bypasses L1/L2
// of both producer and consumer XCDs; 8B store/load is single-instruction
// atomic so tag+payload are indivisible -> no fence/ordering protocol needed).
static __device__ __forceinline__ void st_tag(ull* p, ull v) {
    __hip_atomic_store(p, v, __ATOMIC_RELAXED, __HIP_MEMORY_SCOPE_AGENT);
}
static __device__ __forceinline__ ull ld_tag(const ull* p) {
    return __hip_atomic_load(p, __ATOMIC_RELAXED, __HIP_MEMORY_SCOPE_AGENT);
}

// ---- Kernel A: per-symbol bound of |E| = |exp(A) - 1/Q| via min/max of A ----
__global__ __launch_bounds__(256) void k_minmax(const float* __restrict__ A,
                                                unsigned* __restrict__ smax) {
    const int s  = blockIdx.x >> 3;
    const int i0 = (blockIdx.x & 7) * 64;
    const int tl = threadIdx.x & 127;
    const int rh = threadIdx.x >> 7;
    float mx = -1e30f, mn = 1e30f;
    for (int ro = 0; ro < 64; ro += 2) {
        const int i = i0 + ro + rh;
        float4 a4 = ((const float4*)A)[(size_t)(i * 64 + s) * 128 + tl];
        mx = fmaxf(mx, fmaxf(fmaxf(a4.x, a4.y), fmaxf(a4.z, a4.w)));
        mn = fminf(mn, fminf(fminf(a4.x, a4.y), fminf(a4.z, a4.w)));
    }
    mx = wave_max(mx);
    mn = -wave_max(-mn);
    if ((threadIdx.x & 63) == 0) {
        const float c = 1.0f / 512.0f;
        float se = fmaxf(expf(mx) - c, c - expf(mn));
        atomicMax(&smax[s], __float_as_uint(se));
    }
}

// ---- Kernel B: quantize E to int8, pack transposed layout + rowsums ----
// Epk (int32 units): ((s*32 + j16)*512 + i)*4 + w holds bytes for
// j = 16*j16 + 4*w + {0..3} at state i -> int4 load = 16 consecutive j for one i.
__global__ __launch_bounds__(256) void k_quant(const float* __restrict__ A,
                                               const unsigned* __restrict__ smax,
                                               int* __restrict__ Epk,
                                               int* __restrict__ R) {
    __shared__ int tile[64][129];
    const int s  = blockIdx.x >> 3;
    const int i0 = (blockIdx.x & 7) * 64;
    const float se  = __uint_as_float(smax[s]);
    const float inv = se > 0.0f ? 127.0f / se : 0.0f;
    const float c = 1.0f / 512.0f;
    const int tl = threadIdx.x & 127;
    const int rh = threadIdx.x >> 7;
    for (int ro = 0; ro < 64; ro += 2) {
        const int r = ro + rh;
        const int i = i0 + r;
        float4 a4 = ((const float4*)A)[(size_t)(i * 64 + s) * 128 + tl];
        int q0 = (int)rintf(fminf(fmaxf((expf(a4.x) - c) * inv, -127.0f), 127.0f));
        int q1 = (int)rintf(fminf(fmaxf((expf(a4.y) - c) * inv, -127.0f), 127.0f));
        int q2 = (int)rintf(fminf(fmaxf((expf(a4.z) - c) * inv, -127.0f), 127.0f));
        int q3 = (int)rintf(fminf(fmaxf((expf(a4.w) - c) * inv, -127.0f), 127.0f));
        tile[r][tl] = (q0 & 255) | ((q1 & 255) << 8) | ((q2 & 255) << 16) | ((q3 & 255) << 24);
    }
    __syncthreads();
    if (threadIdx.x < 64) {
        const int r = threadIdx.x;
        int acc = 0;
        #pragma unroll 8
        for (int k = 0; k < 128; ++k) acc = SDOT4(tile[r][k], 0x01010101, acc);
        R[(s << 9) + i0 + r] = acc;
    }
    const int il = threadIdx.x & 63;
    const int jg = threadIdx.x >> 6;
    for (int jo = 0; jo < 8; ++jo) {
        const int j16 = jg * 8 + jo;
        int4 v;
        v.x = tile[il][j16 * 4 + 0];
        v.y = tile[il][j16 * 4 + 1];
        v.z = tile[il][j16 * 4 + 2];
        v.w = tile[il][j16 * 4 + 3];
        ((int4*)Epk)[((size_t)(s * 32 + j16) * 512) + i0 + il] = v;
    }
}

// ---- Main kernel: GS blocks per batch, each owns 128 output rows ----
// Thread t: row irow = g*128 + (t>>3), col-chunk tr = t&7 (64 cols, 4 int4).
// Per-step exchange of alpha + partial sums via parity-double-buffered tagged
// words in the LLC. Producer lead is bounded to 1 step (it must gather OUR
// slice of step k+1 before publishing k+2), so 'tag >= want' on the opposite
// parity buffer never sees an overwrite. All blocks co-resident by capacity.
__global__ __launch_bounds__(1024) void k_fsa(const int* __restrict__ Epk,
                                              const int* __restrict__ R,
                                              const unsigned* __restrict__ smax,
                                              const float* __restrict__ init_w,
                                              const float* __restrict__ fin_w,
                                              const int* __restrict__ xs,
                                              ull* __restrict__ ax,   // [2][BN][QN] tagged alpha
                                              ull* __restrict__ px,   // [2][BN][GS] tagged psums
                                              float* __restrict__ out) {
    __shared__ __align__(16) int qa[QN / 4];
    __shared__ int   xs_l[TN];
    __shared__ float wsum[16];
    __shared__ float se_l[SN];
    __shared__ float m_lds;

    const int t    = threadIdx.x;
    const int b    = blockIdx.x & (BN - 1);   // blockIdx = g*64 + b: siblings share XCD (b%8)
    const int g    = blockIdx.x >> 6;
    const int lane = t & 63, wave = t >> 6;
    const int tr   = t & 7;                   // column chunk (64 cols)
    const int irow = (g << 7) + (t >> 3);     // owned output row

    if (t < TN) xs_l[t] = xs[b * TN + t];
    if (t < SN) se_l[t] = __uint_as_float(smax[t]) * (1.0f / 127.0f);

    const float c  = 1.0f / 512.0f;
    const float Kq = 0.125f;

    // prefetch E, R for step 0 (symbol straight from global; xs_l not visible yet)
    const int s0 = xs[b * TN];
    const int4* __restrict__ Epb = (const int4*)Epk;
    int4 e[4];
    {
        const int4* Ep = Epb + (size_t)(s0 * 32 + tr * 4) * 512 + irow;
        #pragma unroll
        for (int k = 0; k < 4; ++k) e[k] = Ep[(size_t)k * 512];
    }
    int Rv = R[(s0 << 9) + irow];

    // initial alpha: full vector computed redundantly by every block (no exchange)
    float4 av = make_float4(0.f, 0.f, 0.f, 0.f);
    float s4 = 0.0f;
    if (t < 128) {
        const float4 iw = ((const float4*)init_w)[t];
        av.x = expf(iw.x); av.y = expf(iw.y); av.z = expf(iw.z); av.w = expf(iw.w);
        s4 = av.x + av.y + av.z + av.w;
    }
    {
        float ws = wave_sum(s4);
        if (lane == 0) wsum[wave] = ws;
    }
    barrier_lds();

    float m = 0.0f;
    #pragma unroll
    for (int w = 0; w < 16; ++w) m += wsum[w];
    if (t == 0) m_lds = m;
    if (t < 128) {
        const float mu     = m * (1.0f / 512.0f);
        const float inv_sa = 127.0f / (Kq * mu);
        const int q0 = (int)rintf(fminf(fmaxf((av.x - mu) * inv_sa, -127.0f), 127.0f));
        const int q1 = (int)rintf(fminf(fmaxf((av.y - mu) * inv_sa, -127.0f), 127.0f));
        const int q2 = (int)rintf(fminf(fmaxf((av.z - mu) * inv_sa, -127.0f), 127.0f));
        const int q3 = (int)rintf(fminf(fmaxf((av.w - mu) * inv_sa, -127.0f), 127.0f));
        qa[t] = (q0 & 255) | ((q1 & 255) << 8) | ((q2 & 255) << 16) | ((q3 & 255) << 24);
    }
    barrier_lds();

    for (int step = 0; step < TN; ++step) {
        const int s      = xs_l[step];
        const int s_next = xs_l[(step + 1) & (TN - 1)];   // wraps: dummy prefetch at end
        const float mm   = m_lds;

        // dots on prefetched E(s) against quantized alpha
        const int4* qp = (const int4*)qa;
        int acc0 = 0, acc1 = 0, acc2 = 0, acc3 = 0;
        #pragma unroll
        for (int k = 0; k < 4; ++k) {
            const int4 q = qp[tr * 4 + k];
            acc0 = SDOT4(e[k].x, q.x, acc0);
            acc1 = SDOT4(e[k].y, q.y, acc1);
            acc2 = SDOT4(e[k].z, q.z, acc2);
            acc3 = SDOT4(e[k].w, q.w, acc3);
        }
        int acc = (acc0 + acc1) + (acc2 + acc3);
        acc += __shfl_xor(acc, 1, 64);   // reduce over tr (lane bits 0..2)
        acc += __shfl_xor(acc, 2, 64);
        acc += __shfl_xor(acc, 4, 64);

        float outv = 0.0f;
        if (tr == 0) {
            const float mu = mm * (1.0f / 512.0f);
            const float sa = mu * (Kq / 127.0f);
            const float se = se_l[s];
            outv = c * mm + se * (mu * (float)Rv + sa * (float)acc);
            // publish tagged alpha element (tag = step+1, parity buffer (step+1)&1)
            st_tag(ax + (size_t)(((step + 1) & 1) * BN + b) * QN + irow,
                   ((ull)(unsigned)(step + 1) << 32) | (ull)__float_as_uint(outv));
        }
        {
            float ws = wave_sum(outv);
            if (lane == 0) wsum[wave] = ws;
        }
        barrier_lds();   // dots done (qa free), wsum visible

        if (t == 0) {
            float bs = 0.0f;
            #pragma unroll
            for (int w = 0; w < 16; ++w) bs += wsum[w];
            st_tag(px + (size_t)(((step + 1) & 1) * BN + b) * GS + g,
                   ((ull)(unsigned)(step + 1) << 32) | (ull)__float_as_uint(bs));
        }

        // ---- gather: issue polls FIRST, then E/R prefetch, then check ----
        // (in-order vmcnt: this lets the check wait at vmcnt(5), leaving the
        //  64 KiB E-stream for s_next in flight across the sync phase)
        const unsigned want = (unsigned)(step + 1);
        const ull* pp = px + (size_t)(((step + 1) & 1) * BN + b) * GS;
        const ull* ap = ax + (size_t)(((step + 1) & 1) * BN + b) * QN + ((t & 127) << 2);
        ull w0 = 0, w1 = 0, w2 = 0, w3 = 0, a0 = 0, a1 = 0, a2 = 0, a3 = 0;
        if (t < 128) {
            w0 = ld_tag(pp + 0); w1 = ld_tag(pp + 1);
            w2 = ld_tag(pp + 2); w3 = ld_tag(pp + 3);
            a0 = ld_tag(ap + 0); a1 = ld_tag(ap + 1);
            a2 = ld_tag(ap + 2); a3 = ld_tag(ap + 3);
        }
        __builtin_amdgcn_sched_barrier(0);   // keep E-prefetch AFTER the poll issues
        {
            const int4* Epn = Epb + (size_t)(s_next * 32 + tr * 4) * 512 + irow;
            #pragma unroll
            for (int k = 0; k < 4; ++k) e[k] = Epn[(size_t)k * 512];
            Rv = R[(s_next << 9) + irow];
        }
        if (t < 128) {
            while (((unsigned)(w0 >> 32) < want) | ((unsigned)(w1 >> 32) < want) |
                   ((unsigned)(w2 >> 32) < want) | ((unsigned)(w3 >> 32) < want) |
                   ((unsigned)(a0 >> 32) < want) | ((unsigned)(a1 >> 32) < want) |
                   ((unsigned)(a2 >> 32) < want) | ((unsigned)(a3 >> 32) < want)) {
                __builtin_amdgcn_s_sleep(1);
                w0 = ld_tag(pp + 0); w1 = ld_tag(pp + 1);
                w2 = ld_tag(pp + 2); w3 = ld_tag(pp + 3);
                a0 = ld_tag(ap + 0); a1 = ld_tag(ap + 1);
                a2 = ld_tag(ap + 2); a3 = ld_tag(ap + 3);
            }
            m = __uint_as_float((unsigned)w0) + __uint_as_float((unsigned)w1)
              + __uint_as_float((unsigned)w2) + __uint_as_float((unsigned)w3);
            av.x = __uint_as_float((unsigned)a0);
            av.y = __uint_as_float((unsigned)a1);
            av.z = __uint_as_float((unsigned)a2);
            av.w = __uint_as_float((unsigned)a3);
            const float mu2    = m * (1.0f / 512.0f);
            const float inv_sa = 127.0f / (Kq * mu2);
            const int q0 = (int)rintf(fminf(fmaxf((av.x - mu2) * inv_sa, -127.0f), 127.0f));
            const int q1 = (int)rintf(fminf(fmaxf((av.y - mu2) * inv_sa, -127.0f), 127.0f));
            const int q2 = (int)rintf(fminf(fmaxf((av.z - mu2) * inv_sa, -127.0f), 127.0f));
            const int q3 = (int)rintf(fminf(fmaxf((av.w - mu2) * inv_sa, -127.0f), 127.0f));
            qa[t] = (q0 & 255) | ((q1 & 255) << 8) | ((q2 & 255) << 16) | ((q3 & 255) << 24);
            if (t == 0) m_lds = m;
        }
        barrier_lds();   // qa + m_lds ready for next step
    }

    // finalize: g==0 holds gathered final alpha (tag 256) in av (t<128)
    if (g == 0) {
        float v = 0.0f;
        if (t < 128) {
            const float4 fw = ((const float4*)fin_w)[t];
            v = av.x * expf(fw.x) + av.y * expf(fw.y)
              + av.z * expf(fw.z) + av.w * expf(fw.w);
        }
        float ws = wave_sum(v);
        if (lane == 0) wsum[wave] = ws;
        barrier_lds();
        if (t == 0) {
            float tot = 0.0f;
            #pragma unroll
            for (int w = 0; w < 16; ++w) tot += wsum[w];
            out[b] = logf(tot);
        }
    }
}

extern "C" void kernel_launch(void* const* d_in, const int* in_sizes, int n_in,
                              void* d_out, int out_size, void* d_ws, size_t ws_size,
                              hipStream_t stream) {
    const float* A      = (const float*)d_in[0];   // (Q, S, Q) fp32 log-weights
    const float* init_w = (const float*)d_in[1];   // (Q,)
    const float* fin_w  = (const float*)d_in[2];   // (Q,)
    const int*   xs     = (const int*)d_in[3];     // (B, T) int32
    float* out = (float*)d_out;                    // (B,) fp32

    char* ws = (char*)d_ws;
    int*      Epk  = (int*)ws;                                          // 16 MiB
    int*      R    = (int*)(ws + (16u << 20));                          // 128 KiB
    unsigned* smax = (unsigned*)(ws + (16u << 20) + (128u << 10));      // 256 B (1 KiB slot)
    ull*      ax   = (ull*)(ws + (16u << 20) + (128u << 10) + 1024);    // 512 KiB
    ull*      px   = (ull*)(ws + (16u << 20) + (128u << 10) + 1024 + (512u << 10)); // 4 KiB

    // one memset covers smax slot + ax + px (tags must reset every launch:
    // pollers compare 'tag >= step+1' and stale tags from a prior launch
    // would satisfy it with old data)
    hipMemsetAsync(smax, 0, 1024 + (512u << 10) + 4096, stream);
    k_minmax<<<512, 256, 0, stream>>>(A, smax);
    k_quant<<<512, 256, 0, stream>>>(A, smax, Epk, R);
    k_fsa<<<GS * BN, 1024, 0, stream>>>(Epk, R, smax, init_w, fin_w, xs, ax, px, out);
}

// Round 3
// 891.359 us; speedup vs baseline: 1.3015x; 1.2147x over previous
//
#include <hip/hip_runtime.h>

// Problem constants (from reference): Q=512 states, S=64 symbols, B=64, T=256.
#define QN 512
#define SN 64
#define BN 64
#define TN 256
#define GS 4   // row-split: blocks per batch (grid = GS*BN = 256 blocks -> 256 CUs)

typedef unsigned long long ull;

// ---- int8 dot4 (v_dot4_i32_i8) with software fallback ----
#if defined(__has_builtin)
#if __has_builtin(__builtin_amdgcn_sdot4)
#define SDOT4(a, b, c) __builtin_amdgcn_sdot4((a), (b), (c), false)
#endif
#endif
#ifndef SDOT4
static __device__ __forceinline__ int sdot4_sw(int a, int b, int c) {
    c += (int)(signed char)(a)       * (int)(signed char)(b);
    c += (int)(signed char)(a >> 8)  * (int)(signed char)(b >> 8);
    c += (int)(signed char)(a >> 16) * (int)(signed char)(b >> 16);
    c += (int)(signed char)(a >> 24) * (int)(signed char)(b >> 24);
    return c;
}
#define SDOT4(a, b, c) sdot4_sw((a), (b), (c))
#endif

static __device__ __forceinline__ float wave_sum(float v) {
    #pragma unroll
    for (int o = 32; o > 0; o >>= 1) v += __shfl_xor(v, o, 64);
    return v;
}
static __device__ __forceinline__ float wave_max(float v) {
    #pragma unroll
    for (int o = 32; o > 0; o >>= 1) v = fmaxf(v, __shfl_xor(v, o, 64));
    return v;
}

// Barrier with LDS-only drain: waits lgkmcnt(0) but leaves global loads in
// flight (vmcnt untouched) so cross-step register prefetch survives the
// barrier. imm encoding (gfx9/CDNA): vm[3:0]=0xF, exp[6:4]=7, lgkm[11:8]=0,
// vm[15:14]=3 -> 0xC07F.
static __device__ __forceinline__ void barrier_lds(void) {
    __builtin_amdgcn_s_waitcnt(0xC07F);
    __builtin_amdgcn_s_barrier();
}

// Tagged-word exchange through the LLC (agent scope => sc0 sc1: bypasses L1
// and the XCD-private L2 on both sides; 8B single-instruction access is
// indivisible so tag+payload need no ordering protocol). PROVEN in round 1.
// NOTE round-2 post-mortem: do NOT replace the poll with flat/lgkm tricks --
// flat's lgkm decrement does not guarantee data return; only vmcnt does.
static __device__ __forceinline__ void st_tag(ull* p, ull v) {
    __hip_atomic_store(p, v, __ATOMIC_RELAXED, __HIP_MEMORY_SCOPE_AGENT);
}
static __device__ __forceinline__ ull ld_tag(const ull* p) {
    return __hip_atomic_load(p, __ATOMIC_RELAXED, __HIP_MEMORY_SCOPE_AGENT);
}

// ---- Kernel A: per-symbol bound of |E| = |exp(A) - 1/Q| via min/max of A ----
__global__ __launch_bounds__(256) void k_minmax(const float* __restrict__ A,
                                                unsigned* __restrict__ smax) {
    const int s  = blockIdx.x >> 3;
    const int i0 = (blockIdx.x & 7) * 64;
    const int tl = threadIdx.x & 127;
    const int rh = threadIdx.x >> 7;
    float mx = -1e30f, mn = 1e30f;
    for (int ro = 0; ro < 64; ro += 2) {
        const int i = i0 + ro + rh;
        float4 a4 = ((const float4*)A)[(size_t)(i * 64 + s) * 128 + tl];
        mx = fmaxf(mx, fmaxf(fmaxf(a4.x, a4.y), fmaxf(a4.z, a4.w)));
        mn = fminf(mn, fminf(fminf(a4.x, a4.y), fminf(a4.z, a4.w)));
    }
    mx = wave_max(mx);
    mn = -wave_max(-mn);
    if ((threadIdx.x & 63) == 0) {
        const float c = 1.0f / 512.0f;
        float se = fmaxf(expf(mx) - c, c - expf(mn));
        atomicMax(&smax[s], __float_as_uint(se));
    }
}

// ---- Kernel B: quantize E to int8, pack transposed layout + rowsums ----
// Epk (int4 units): (s*32 + j16)*512 + i holds bytes for columns
// j = 16*j16 + {0..15} at output row i.
__global__ __launch_bounds__(256) void k_quant(const float* __restrict__ A,
                                               const unsigned* __restrict__ smax,
                                               int* __restrict__ Epk,
                                               int* __restrict__ R) {
    __shared__ int tile[64][129];
    const int s  = blockIdx.x >> 3;
    const int i0 = (blockIdx.x & 7) * 64;
    const float se  = __uint_as_float(smax[s]);
    const float inv = se > 0.0f ? 127.0f / se : 0.0f;
    const float c = 1.0f / 512.0f;
    const int tl = threadIdx.x & 127;
    const int rh = threadIdx.x >> 7;
    for (int ro = 0; ro < 64; ro += 2) {
        const int r = ro + rh;
        const int i = i0 + r;
        float4 a4 = ((const float4*)A)[(size_t)(i * 64 + s) * 128 + tl];
        int q0 = (int)rintf(fminf(fmaxf((expf(a4.x) - c) * inv, -127.0f), 127.0f));
        int q1 = (int)rintf(fminf(fmaxf((expf(a4.y) - c) * inv, -127.0f), 127.0f));
        int q2 = (int)rintf(fminf(fmaxf((expf(a4.z) - c) * inv, -127.0f), 127.0f));
        int q3 = (int)rintf(fminf(fmaxf((expf(a4.w) - c) * inv, -127.0f), 127.0f));
        tile[r][tl] = (q0 & 255) | ((q1 & 255) << 8) | ((q2 & 255) << 16) | ((q3 & 255) << 24);
    }
    __syncthreads();
    if (threadIdx.x < 64) {
        const int r = threadIdx.x;
        int acc = 0;
        #pragma unroll 8
        for (int k = 0; k < 128; ++k) acc = SDOT4(tile[r][k], 0x01010101, acc);
        R[(s << 9) + i0 + r] = acc;
    }
    const int il = threadIdx.x & 63;
    const int jg = threadIdx.x >> 6;
    for (int jo = 0; jo < 8; ++jo) {
        const int j16 = jg * 8 + jo;
        int4 v;
        v.x = tile[il][j16 * 4 + 0];
        v.y = tile[il][j16 * 4 + 1];
        v.z = tile[il][j16 * 4 + 2];
        v.w = tile[il][j16 * 4 + 3];
        ((int4*)Epk)[((size_t)(s * 32 + j16) * 512) + i0 + il] = v;
    }
}

// ---- Main kernel: wave-specialized. 8 compute waves + 8 sync waves ----
// Compute thread t<512: row irow = g*128 + (t>>2), col-chunk tr = t&3
//   (128 cols = 8 int4 E-frags). Issues ALL E/R prefetch + the publish; its
//   per-wave vmcnt queue holds only prefetch, which stays in flight across
//   barrier_lds. Never waits vmcnt for sync.
// Sync thread t>=512: owns ONE alpha word u = t-512. Its vmcnt queue holds
//   only the 1-word tagged poll -> each retry costs one LLC round trip (the
//   round-1 bottleneck was retry polls queued behind the 64 KiB E-stream in
//   the in-order per-wave vmcnt queue). Gather + m-reduce + re-quantize run
//   concurrently with the dots.
// qa/m double-buffered by step parity; ax tagged words double-buffered by
// parity. Producer lead bounded to 1 step (publish k+2 requires this block
// gathered k+1, requires all siblings published k+1, requires they gathered
// k), so 'tag >= want' never observes an overwrite. 256 blocks x 1024 thr
// co-resident (VGPR<=128) => poll loops cannot deadlock.
__global__ __launch_bounds__(1024) void k_fsa(const int* __restrict__ Epk,
                                              const int* __restrict__ R,
                                              const unsigned* __restrict__ smax,
                                              const float* __restrict__ init_w,
                                              const float* __restrict__ fin_w,
                                              const int* __restrict__ xs,
                                              ull* __restrict__ ax,   // [2][BN][QN] tagged alpha
                                              float* __restrict__ out) {
    __shared__ __align__(16) int qa[2][QN / 4];   // int8 alpha, parity buffers
    __shared__ int   xs_l[TN];
    __shared__ float wsum[8];
    __shared__ float se_l[SN];
    __shared__ float mb[2];                       // block sum m, parity buffers

    const int t    = threadIdx.x;
    const int b    = blockIdx.x & (BN - 1);   // blockIdx = g*64 + b
    const int g    = blockIdx.x >> 6;
    const int lane = t & 63, wave = t >> 6;
    const int tr   = t & 3;                   // compute: col chunk (128 cols)
    const int irow = (g << 7) + (t >> 2);     // compute: owned output row
    const int u    = t - 512;                 // sync: owned alpha index

    if (t < TN) xs_l[t] = xs[b * TN + t];
    if (t < SN) se_l[t] = __uint_as_float(smax[t]) * (1.0f / 127.0f);

    const float c  = 1.0f / 512.0f;
    const float Kq = 0.125f;

    const int4* __restrict__ Epb = (const int4*)Epk;
    int4 e[8];
    int Rv = 0;
    float av = 0.0f;   // sync: gathered alpha value

    if (t < 512) {
        // prefetch E, R for step 0 (symbol straight from global)
        const int s0 = xs[b * TN];
        const int4* Ep = Epb + (size_t)(s0 * 32 + tr * 8) * 512 + irow;
        #pragma unroll
        for (int k = 0; k < 8; ++k) e[k] = Ep[(size_t)k * 512];
        if (tr == 0) Rv = R[(s0 << 9) + irow];
    } else {
        // initial alpha: one element per sync thread, computed redundantly
        av = expf(init_w[u]);
        float ws = wave_sum(av);
        if (lane == 0) wsum[wave - 8] = ws;
    }
    barrier_lds();
    if (t >= 512) {
        float m0 = 0.0f;
        #pragma unroll
        for (int w = 0; w < 8; ++w) m0 += wsum[w];
        const float mu     = m0 * (1.0f / 512.0f);
        const float inv_sa = 127.0f / (Kq * mu);
        const int q = (int)rintf(fminf(fmaxf((av - mu) * inv_sa, -127.0f), 127.0f));
        ((char*)qa)[u] = (char)q;             // parity-0 buffer, byte u
        if (u == 0) mb[0] = m0;
    }
    barrier_lds();

    for (int step = 0; step < TN; ++step) {
        const int p = step & 1;
        if (t < 512) {
            const int s_next = xs_l[(step + 1) & (TN - 1)];  // wraps: dummy at end
            const float mm   = mb[p];
            // dots on prefetched E(s); re-issue each e-slot for s_next
            const int4* qp  = (const int4*)qa[p];
            const int4* Epn = Epb + (size_t)(s_next * 32 + tr * 8) * 512 + irow;
            int acc0 = 0, acc1 = 0, acc2 = 0, acc3 = 0;
            #pragma unroll
            for (int k = 0; k < 8; ++k) {
                const int4 q = qp[tr * 8 + k];
                acc0 = SDOT4(e[k].x, q.x, acc0);
                acc1 = SDOT4(e[k].y, q.y, acc1);
                acc2 = SDOT4(e[k].z, q.z, acc2);
                acc3 = SDOT4(e[k].w, q.w, acc3);
                e[k] = Epn[(size_t)k * 512];
            }
            __builtin_amdgcn_sched_barrier(0);   // pin E issue before publish
            int acc = (acc0 + acc1) + (acc2 + acc3);
            acc += __shfl_xor(acc, 1, 64);       // reduce over tr (lane bits 0..1)
            acc += __shfl_xor(acc, 2, 64);
            if (tr == 0) {
                const int s   = xs_l[step];
                const int RvC = Rv;
                Rv = R[(s_next << 9) + irow];    // prefetch next R
                const float mu = mm * (1.0f / 512.0f);
                const float sa = mu * (Kq / 127.0f);
                const float se = se_l[s];
                const float outv = c * mm + se * (mu * (float)RvC + sa * (float)acc);
                st_tag(ax + (size_t)(((p ^ 1)) * BN + b) * QN + irow,
                       ((ull)(unsigned)(step + 1) << 32) | (ull)__float_as_uint(outv));
            }
        } else {
            // gather step+1 (parity p^1): poll own word; retries are cheap
            // (this wave's vmcnt queue contains nothing else)
            const unsigned want = (unsigned)(step + 1);
            const ull* ap = ax + (size_t)((p ^ 1) * BN + b) * QN + u;
            ull a = ld_tag(ap);
            while ((unsigned)(a >> 32) < want) {
                __builtin_amdgcn_s_sleep(1);
                a = ld_tag(ap);
            }
            av = __uint_as_float((unsigned)a);
            float ws = wave_sum(av);
            if (lane == 0) wsum[wave - 8] = ws;
        }
        barrier_lds();   // barrier1: wsum ready; dots done (qa[p] free next iter)

        if (t >= 512) {
            float m = 0.0f;
            #pragma unroll
            for (int w = 0; w < 8; ++w) m += wsum[w];    // same tree in all blocks
            const float mu     = m * (1.0f / 512.0f);
            const float inv_sa = 127.0f / (Kq * mu);
            const int q = (int)rintf(fminf(fmaxf((av - mu) * inv_sa, -127.0f), 127.0f));
            ((char*)qa)[(p ^ 1) * QN + u] = (char)q;
            if (u == 0) mb[p ^ 1] = m;
        }
        barrier_lds();   // barrier2: qa[p^1] + mb[p^1] ready for next step
    }

    // finalize: sync threads hold gathered final alpha (tag 256) in av
    {
        float v = 0.0f;
        if (t >= 512) {
            v = av * expf(fin_w[u]);
            float ws = wave_sum(v);
            if (lane == 0) wsum[wave - 8] = ws;
        }
        barrier_lds();
        if (g == 0 && t == 512) {
            float tot = 0.0f;
            #pragma unroll
            for (int w = 0; w < 8; ++w) tot += wsum[w];
            out[b] = logf(tot);
        }
    }
}

extern "C" void kernel_launch(void* const* d_in, const int* in_sizes, int n_in,
                              void* d_out, int out_size, void* d_ws, size_t ws_size,
                              hipStream_t stream) {
    const float* A      = (const float*)d_in[0];   // (Q, S, Q) fp32 log-weights
    const float* init_w = (const float*)d_in[1];   // (Q,)
    const float* fin_w  = (const float*)d_in[2];   // (Q,)
    const int*   xs     = (const int*)d_in[3];     // (B, T) int32
    float* out = (float*)d_out;                    // (B,) fp32

    char* ws = (char*)d_ws;
    int*      Epk  = (int*)ws;                                          // 16 MiB
    int*      R    = (int*)(ws + (16u << 20));                          // 128 KiB
    unsigned* smax = (unsigned*)(ws + (16u << 20) + (128u << 10));      // 256 B (1 KiB slot)
    ull*      ax   = (ull*)(ws + (16u << 20) + (128u << 10) + 1024);    // 512 KiB

    // tags must reset every launch: pollers compare 'tag >= step+1' and stale
    // tags from a prior launch would satisfy it with old data
    hipMemsetAsync(smax, 0, 1024 + (512u << 10), stream);
    k_minmax<<<512, 256, 0, stream>>>(A, smax);
    k_quant<<<512, 256, 0, stream>>>(A, smax, Epk, R);
    k_fsa<<<GS * BN, 1024, 0, stream>>>(Epk, R, smax, init_w, fin_w, xs, ax, out);
}

// Round 4
// 670.537 us; speedup vs baseline: 1.7302x; 1.3293x over previous
//
#include <hip/hip_runtime.h>

// Problem constants (from reference): Q=512 states, S=64 symbols, B=64, T=256.
#define QN 512
#define SN 64
#define BN 64
#define TN 256
#define GS 4   // row-split: blocks per batch (grid = GS*BN = 256 blocks -> 256 CUs)

typedef unsigned long long ull;

// ---- int8 dot4 (v_dot4_i32_i8) with software fallback ----
#if defined(__has_builtin)
#if __has_builtin(__builtin_amdgcn_sdot4)
#define SDOT4(a, b, c) __builtin_amdgcn_sdot4((a), (b), (c), false)
#endif
#endif
#ifndef SDOT4
static __device__ __forceinline__ int sdot4_sw(int a, int b, int c) {
    c += (int)(signed char)(a)       * (int)(signed char)(b);
    c += (int)(signed char)(a >> 8)  * (int)(signed char)(b >> 8);
    c += (int)(signed char)(a >> 16) * (int)(signed char)(b >> 16);
    c += (int)(signed char)(a >> 24) * (int)(signed char)(b >> 24);
    return c;
}
#define SDOT4(a, b, c) sdot4_sw((a), (b), (c))
#endif

// signed-nibble unpack: bytes of (x & 0x0F..) are in [0,15]; ^8 then -8 per
// byte maps to [-8,7] two's-complement bytes; no cross-byte borrow possible.
#define NIB_LO(x) ((((x) & 0x0F0F0F0F) ^ 0x08080808) - 0x08080808)
#define NIB_HI(x) (((((x) >> 4) & 0x0F0F0F0F) ^ 0x08080808) - 0x08080808)

static __device__ __forceinline__ float wave_sum(float v) {
    #pragma unroll
    for (int o = 32; o > 0; o >>= 1) v += __shfl_xor(v, o, 64);
    return v;
}
static __device__ __forceinline__ float wave_max(float v) {
    #pragma unroll
    for (int o = 32; o > 0; o >>= 1) v = fmaxf(v, __shfl_xor(v, o, 64));
    return v;
}

// Barrier with LDS-only drain: waits lgkmcnt(0) but leaves global loads in
// flight (vmcnt untouched) so cross-step register prefetch survives the
// barrier. imm encoding (gfx9/CDNA): vm[3:0]=0xF, exp[6:4]=7, lgkm[11:8]=0,
// vm[15:14]=3 -> 0xC07F.
static __device__ __forceinline__ void barrier_lds(void) {
    __builtin_amdgcn_s_waitcnt(0xC07F);
    __builtin_amdgcn_s_barrier();
}

// Tagged-word exchange through the LLC (agent scope => sc0 sc1: bypasses L1
// and the XCD-private L2 on both sides; 8B single-instruction access is
// indivisible so tag+payload need no ordering protocol). PROVEN rounds 1/3.
// Round-2 post-mortem: do NOT replace with flat/lgkm tricks -- flat's lgkm
// decrement does not guarantee data return; only vmcnt does.
static __device__ __forceinline__ void st_tag(ull* p, ull v) {
    __hip_atomic_store(p, v, __ATOMIC_RELAXED, __HIP_MEMORY_SCOPE_AGENT);
}
static __device__ __forceinline__ ull ld_tag(const ull* p) {
    return __hip_atomic_load(p, __ATOMIC_RELAXED, __HIP_MEMORY_SCOPE_AGENT);
}

// ---- Kernel A: per-symbol bound of |E| = |exp(A) - 1/Q| via min/max of A ----
__global__ __launch_bounds__(256) void k_minmax(const float* __restrict__ A,
                                                unsigned* __restrict__ smax) {
    const int s  = blockIdx.x >> 3;
    const int i0 = (blockIdx.x & 7) * 64;
    const int tl = threadIdx.x & 127;
    const int rh = threadIdx.x >> 7;
    float mx = -1e30f, mn = 1e30f;
    for (int ro = 0; ro < 64; ro += 2) {
        const int i = i0 + ro + rh;
        float4 a4 = ((const float4*)A)[(size_t)(i * 64 + s) * 128 + tl];
        mx = fmaxf(mx, fmaxf(fmaxf(a4.x, a4.y), fmaxf(a4.z, a4.w)));
        mn = fminf(mn, fminf(fminf(a4.x, a4.y), fminf(a4.z, a4.w)));
    }
    mx = wave_max(mx);
    mn = -wave_max(-mn);
    if ((threadIdx.x & 63) == 0) {
        const float c = 1.0f / 512.0f;
        float se = fmaxf(expf(mx) - c, c - expf(mn));
        atomicMax(&smax[s], __float_as_uint(se));
    }
}

// ---- Kernel B: quantize E to int4 nibbles + EXACT fp32 rowsums ----
// Epk (int4-vector units): (s*16 + j32)*512 + i covers the 32-column block
// j = 32*j32 + {0..31} at output row i: word w's LO nibbles are cols
// 32*j32+4w+{0..3}, HI nibbles are cols 32*j32+16+4w+{0..3}.
// ES[s][i] = sum_j E[i,j] in fp32 (exact): the mean-term of the int4
// quantization error cancels against it, leaving only error x alpha-deviation.
__global__ __launch_bounds__(256) void k_quant(const float* __restrict__ A,
                                               const unsigned* __restrict__ smax,
                                               int* __restrict__ Epk,
                                               float* __restrict__ ES) {
    __shared__ int tile[64][129];   // int8 bytes of e4 values in [-7,7]
    __shared__ float fsum[64];
    const int s  = blockIdx.x >> 3;
    const int i0 = (blockIdx.x & 7) * 64;
    const float se  = __uint_as_float(smax[s]);
    const float inv = se > 0.0f ? 7.0f / se : 0.0f;   // int4 grid: se4 = se/7
    const float c = 1.0f / 512.0f;
    const int tl = threadIdx.x & 127;
    const int rh = threadIdx.x >> 7;
    if (threadIdx.x < 64) fsum[threadIdx.x] = 0.0f;
    __syncthreads();
    for (int ro = 0; ro < 64; ro += 2) {
        const int r = ro + rh;
        const int i = i0 + r;
        float4 a4 = ((const float4*)A)[(size_t)(i * 64 + s) * 128 + tl];
        const float e0 = expf(a4.x) - c, e1 = expf(a4.y) - c;
        const float e2 = expf(a4.z) - c, e3 = expf(a4.w) - c;
        int q0 = (int)rintf(fminf(fmaxf(e0 * inv, -7.0f), 7.0f));
        int q1 = (int)rintf(fminf(fmaxf(e1 * inv, -7.0f), 7.0f));
        int q2 = (int)rintf(fminf(fmaxf(e2 * inv, -7.0f), 7.0f));
        int q3 = (int)rintf(fminf(fmaxf(e3 * inv, -7.0f), 7.0f));
        tile[r][tl] = (q0 & 255) | ((q1 & 255) << 8) | ((q2 & 255) << 16) | ((q3 & 255) << 24);
        // exact fp32 rowsum of E (each wave covers half a row's columns)
        float ws = wave_sum(e0 + e1 + e2 + e3);
        if ((threadIdx.x & 63) == 0) atomicAdd(&fsum[r], ws);
    }
    __syncthreads();
    if (threadIdx.x < 64) ES[(s << 9) + i0 + threadIdx.x] = fsum[threadIdx.x];
    // pack nibble pairs (col j with col j+16 of the same 32-block) and write
    const int il = threadIdx.x & 63;
    const int jg = threadIdx.x >> 6;          // 0..3
    for (int jo = 0; jo < 4; ++jo) {
        const int j32 = jg * 4 + jo;
        int4 v;
        v.x = (tile[il][8 * j32 + 0] & 0x0F0F0F0F) | ((tile[il][8 * j32 + 4] & 0x0F0F0F0F) << 4);
        v.y = (tile[il][8 * j32 + 1] & 0x0F0F0F0F) | ((tile[il][8 * j32 + 5] & 0x0F0F0F0F) << 4);
        v.z = (tile[il][8 * j32 + 2] & 0x0F0F0F0F) | ((tile[il][8 * j32 + 6] & 0x0F0F0F0F) << 4);
        v.w = (tile[il][8 * j32 + 3] & 0x0F0F0F0F) | ((tile[il][8 * j32 + 7] & 0x0F0F0F0F) << 4);
        ((int4*)Epk)[((size_t)(s * 16 + j32) * 512) + i0 + il] = v;
    }
}

// ---- Main kernel: wave-specialized (proven round 3), int4 E-stream ----
// Compute thread t<512: row irow = g*128 + (t>>2), col-chunk tr = t&3
//   (128 cols = 4 int4 nibble-loads = 32 KiB/block/step, HALF of round 3).
// Sync thread t>=512: owns ONE alpha word u = t-512; its vmcnt queue holds
//   only the 1-word tagged poll (retry = one LLC round trip).
// outv = c*m + mu*(ES_i + se_l[s]*acc): ES exact fp32 rowsum kills the
// quantization mean-term; se_l = smax*Kq/(127*7) covers sa*se4.
__global__ __launch_bounds__(1024) void k_fsa(const int* __restrict__ Epk,
                                              const float* __restrict__ ES,
                                              const unsigned* __restrict__ smax,
                                              const float* __restrict__ init_w,
                                              const float* __restrict__ fin_w,
                                              const int* __restrict__ xs,
                                              ull* __restrict__ ax,   // [2][BN][QN] tagged alpha
                                              float* __restrict__ out) {
    __shared__ __align__(16) int qa[2][QN / 4];   // int8 alpha, parity buffers
    __shared__ int   xs_l[TN];
    __shared__ float wsum[8];
    __shared__ float se_l[SN];
    __shared__ float mb[2];                       // block sum m, parity buffers

    const int t    = threadIdx.x;
    const int b    = blockIdx.x & (BN - 1);   // blockIdx = g*64 + b
    const int g    = blockIdx.x >> 6;
    const int lane = t & 63, wave = t >> 6;
    const int tr   = t & 3;                   // compute: col chunk (128 cols)
    const int irow = (g << 7) + (t >> 2);     // compute: owned output row
    const int u    = t - 512;                 // sync: owned alpha index

    if (t < TN) xs_l[t] = xs[b * TN + t];
    if (t < SN) se_l[t] = __uint_as_float(smax[t]) * (0.125f / 889.0f); // Kq/(127*7)

    const float c  = 1.0f / 512.0f;
    const float Kq = 0.125f;

    const int4* __restrict__ Epb = (const int4*)Epk;
    int4 e[4];
    float ESv = 0.0f;
    float av = 0.0f;   // sync: gathered alpha value

    if (t < 512) {
        // prefetch E, ES for step 0 (symbol straight from global)
        const int s0 = xs[b * TN];
        const int4* Ep = Epb + (size_t)(s0 * 16 + tr * 4) * 512 + irow;
        #pragma unroll
        for (int k = 0; k < 4; ++k) e[k] = Ep[(size_t)k * 512];
        if (tr == 0) ESv = ES[(s0 << 9) + irow];
    } else {
        // initial alpha: one element per sync thread, computed redundantly
        av = expf(init_w[u]);
        float ws = wave_sum(av);
        if (lane == 0) wsum[wave - 8] = ws;
    }
    barrier_lds();
    if (t >= 512) {
        float m0 = 0.0f;
        #pragma unroll
        for (int w = 0; w < 8; ++w) m0 += wsum[w];
        const float mu     = m0 * (1.0f / 512.0f);
        const float inv_sa = 127.0f / (Kq * mu);
        const int q = (int)rintf(fminf(fmaxf((av - mu) * inv_sa, -127.0f), 127.0f));
        ((char*)qa)[u] = (char)q;             // parity-0 buffer, byte u
        if (u == 0) mb[0] = m0;
    }
    barrier_lds();

    for (int step = 0; step < TN; ++step) {
        const int p = step & 1;
        if (t < 512) {
            const int s_next = xs_l[(step + 1) & (TN - 1)];  // wraps: dummy at end
            const float mm   = mb[p];
            // dots on prefetched int4 E(s); re-issue each e-slot for s_next
            const int4* qp  = (const int4*)qa[p];
            const int4* Epn = Epb + (size_t)(s_next * 16 + tr * 4) * 512 + irow;
            int acc0 = 0, acc1 = 0, acc2 = 0, acc3 = 0;
            #pragma unroll
            for (int k = 0; k < 4; ++k) {
                const int4 E4  = e[k];
                e[k] = Epn[(size_t)k * 512];
                const int4 qlo = qp[2 * (4 * tr + k) + 0];   // cols 32j+0..15
                const int4 qhi = qp[2 * (4 * tr + k) + 1];   // cols 32j+16..31
                acc0 = SDOT4(NIB_LO(E4.x), qlo.x, acc0);
                acc1 = SDOT4(NIB_HI(E4.x), qhi.x, acc1);
                acc2 = SDOT4(NIB_LO(E4.y), qlo.y, acc2);
                acc3 = SDOT4(NIB_HI(E4.y), qhi.y, acc3);
                acc0 = SDOT4(NIB_LO(E4.z), qlo.z, acc0);
                acc1 = SDOT4(NIB_HI(E4.z), qhi.z, acc1);
                acc2 = SDOT4(NIB_LO(E4.w), qlo.w, acc2);
                acc3 = SDOT4(NIB_HI(E4.w), qhi.w, acc3);
            }
            __builtin_amdgcn_sched_barrier(0);   // pin E issue before publish
            int acc = (acc0 + acc1) + (acc2 + acc3);
            acc += __shfl_xor(acc, 1, 64);       // reduce over tr (lane bits 0..1)
            acc += __shfl_xor(acc, 2, 64);
            if (tr == 0) {
                const int s     = xs_l[step];
                const float ESc = ESv;
                ESv = ES[(s_next << 9) + irow];  // prefetch next ES
                const float mu = mm * (1.0f / 512.0f);
                const float outv = c * mm + mu * (ESc + se_l[s] * (float)acc);
                st_tag(ax + (size_t)(((p ^ 1)) * BN + b) * QN + irow,
                       ((ull)(unsigned)(step + 1) << 32) | (ull)__float_as_uint(outv));
            }
        } else {
            // gather step+1 (parity p^1): poll own word; retries are cheap
            // (this wave's vmcnt queue contains nothing else)
            const unsigned want = (unsigned)(step + 1);
            const ull* ap = ax + (size_t)((p ^ 1) * BN + b) * QN + u;
            ull a = ld_tag(ap);
            while ((unsigned)(a >> 32) < want) {
                __builtin_amdgcn_s_sleep(1);
                a = ld_tag(ap);
            }
            av = __uint_as_float((unsigned)a);
            float ws = wave_sum(av);
            if (lane == 0) wsum[wave - 8] = ws;
        }
        barrier_lds();   // barrier1: wsum ready; dots done (qa[p] free next iter)

        if (t >= 512) {
            float m = 0.0f;
            #pragma unroll
            for (int w = 0; w < 8; ++w) m += wsum[w];    // same tree in all blocks
            const float mu     = m * (1.0f / 512.0f);
            const float inv_sa = 127.0f / (Kq * mu);
            const int q = (int)rintf(fminf(fmaxf((av - mu) * inv_sa, -127.0f), 127.0f));
            ((char*)qa)[(p ^ 1) * QN + u] = (char)q;
            if (u == 0) mb[p ^ 1] = m;
        }
        barrier_lds();   // barrier2: qa[p^1] + mb[p^1] ready for next step
    }

    // finalize: sync threads hold gathered final alpha (tag 256) in av
    {
        float v = 0.0f;
        if (t >= 512) {
            v = av * expf(fin_w[u]);
            float ws = wave_sum(v);
            if (lane == 0) wsum[wave - 8] = ws;
        }
        barrier_lds();
        if (g == 0 && t == 512) {
            float tot = 0.0f;
            #pragma unroll
            for (int w = 0; w < 8; ++w) tot += wsum[w];
            out[b] = logf(tot);
        }
    }
}

extern "C" void kernel_launch(void* const* d_in, const int* in_sizes, int n_in,
                              void* d_out, int out_size, void* d_ws, size_t ws_size,
                              hipStream_t stream) {
    const float* A      = (const float*)d_in[0];   // (Q, S, Q) fp32 log-weights
    const float* init_w = (const float*)d_in[1];   // (Q,)
    const float* fin_w  = (const float*)d_in[2];   // (Q,)
    const int*   xs     = (const int*)d_in[3];     // (B, T) int32
    float* out = (float*)d_out;                    // (B,) fp32

    char* ws = (char*)d_ws;
    int*      Epk  = (int*)ws;                                          // 8 MiB (int4 nibbles)
    float*    ES   = (float*)(ws + (8u << 20));                         // 128 KiB fp32 rowsums
    unsigned* smax = (unsigned*)(ws + (8u << 20) + (128u << 10));       // 256 B (1 KiB slot)
    ull*      ax   = (ull*)(ws + (8u << 20) + (128u << 10) + 1024);     // 512 KiB

    // tags must reset every launch: pollers compare 'tag >= step+1' and stale
    // tags from a prior launch would satisfy it with old data
    hipMemsetAsync(smax, 0, 1024 + (512u << 10), stream);
    k_minmax<<<512, 256, 0, stream>>>(A, smax);
    k_quant<<<512, 256, 0, stream>>>(A, smax, Epk, ES);
    k_fsa<<<GS * BN, 1024, 0, stream>>>(Epk, ES, smax, init_w, fin_w, xs, ax, out);
}

// Round 7
// 651.748 us; speedup vs baseline: 1.7800x; 1.0288x over previous
//
#include <hip/hip_runtime.h>

// Problem constants (from reference): Q=512 states, S=64 symbols, B=64, T=256.
#define QN 512
#define SN 64
#define BN 64
#define TN 256
#define GS 4   // row/col-split: blocks per batch (grid = GS*BN = 256 blocks)

typedef unsigned long long ull;

// ---- int8 dot4 (v_dot4_i32_i8) with software fallback ----
#if defined(__has_builtin)
#if __has_builtin(__builtin_amdgcn_sdot4)
#define SDOT4(a, b, c) __builtin_amdgcn_sdot4((a), (b), (c), false)
#endif
#endif
#ifndef SDOT4
static __device__ __forceinline__ int sdot4_sw(int a, int b, int c) {
    c += (int)(signed char)(a)       * (int)(signed char)(b);
    c += (int)(signed char)(a >> 8)  * (int)(signed char)(b >> 8);
    c += (int)(signed char)(a >> 16) * (int)(signed char)(b >> 16);
    c += (int)(signed char)(a >> 24) * (int)(signed char)(b >> 24);
    return c;
}
#define SDOT4(a, b, c) sdot4_sw((a), (b), (c))
#endif

// signed-nibble unpack: bytes of (x & 0x0F..) are in [0,15]; ^8 then -8 per
// byte maps to [-8,7] two's-complement bytes; no cross-byte borrow possible.
#define NIB_LO(x) ((((x) & 0x0F0F0F0F) ^ 0x08080808) - 0x08080808)
#define NIB_HI(x) (((((x) >> 4) & 0x0F0F0F0F) ^ 0x08080808) - 0x08080808)

static __device__ __forceinline__ float wave_sum(float v) {
    #pragma unroll
    for (int o = 32; o > 0; o >>= 1) v += __shfl_xor(v, o, 64);
    return v;
}
static __device__ __forceinline__ float wave_max(float v) {
    #pragma unroll
    for (int o = 32; o > 0; o >>= 1) v = fmaxf(v, __shfl_xor(v, o, 64));
    return v;
}

// Barrier with LDS-only drain: waits lgkmcnt(0) but leaves global loads in
// flight (vmcnt untouched) so cross-step register prefetch survives the
// barrier. imm encoding (gfx9/CDNA): vm[3:0]=0xF, exp[6:4]=7, lgkm[11:8]=0,
// vm[15:14]=3 -> 0xC07F.
static __device__ __forceinline__ void barrier_lds(void) {
    __builtin_amdgcn_s_waitcnt(0xC07F);
    __builtin_amdgcn_s_barrier();
}

// Exchange transport: agent-scope atomics (sc0 sc1 -> LLC write-through /
// LLC read). PROVEN rounds 1/3/4. Round-2 post-mortem: flat/lgkm polling is
// unsound (lgkm decrement does not guarantee data return). Round-6
// post-mortem: the sc0-only L2 "fast path" is UNSOUND -- cross-XCD consumers
// retain clean stale L2 lines with no invalidation protocol; a t=0 coherence
// probe cannot certify t>0. LLC transport only.
static __device__ __forceinline__ void st_tag(ull* p, ull v) {
    __hip_atomic_store(p, v, __ATOMIC_RELAXED, __HIP_MEMORY_SCOPE_AGENT);
}
static __device__ __forceinline__ ull ld_tag(const ull* p) {
    return __hip_atomic_load(p, __ATOMIC_RELAXED, __HIP_MEMORY_SCOPE_AGENT);
}

#define POLL_GUARD (1 << 20)   // turns any protocol error into a visible
                               // wrong answer instead of a hang

// ---- Kernel A: per-symbol bound of |E| = |exp(A) - 1/Q| via min/max of A ----
__global__ __launch_bounds__(256) void k_minmax(const float* __restrict__ A,
                                                unsigned* __restrict__ smax) {
    const int s  = blockIdx.x >> 3;
    const int i0 = (blockIdx.x & 7) * 64;
    const int tl = threadIdx.x & 127;
    const int rh = threadIdx.x >> 7;
    float mx = -1e30f, mn = 1e30f;
    for (int ro = 0; ro < 64; ro += 2) {
        const int i = i0 + ro + rh;
        float4 a4 = ((const float4*)A)[(size_t)(i * 64 + s) * 128 + tl];
        mx = fmaxf(mx, fmaxf(fmaxf(a4.x, a4.y), fmaxf(a4.z, a4.w)));
        mn = fminf(mn, fminf(fminf(a4.x, a4.y), fminf(a4.z, a4.w)));
    }
    mx = wave_max(mx);
    mn = -wave_max(-mn);
    if ((threadIdx.x & 63) == 0) {
        const float c = 1.0f / 512.0f;
        float se = fmaxf(expf(mx) - c, c - expf(mn));
        atomicMax(&smax[s], __float_as_uint(se));
    }
}

// ---- Kernel B: int4 nibbles + EXACT fp32 per-chunk row sums ----
// Epk (int4-vector units): (s*16 + j32)*512 + i covers the 32-column block
// j = 32*j32 + {0..31} at output row i: word w's LO nibbles are cols
// 32*j32+4w+{0..3}, HI nibbles are cols 32*j32+16+4w+{0..3}.
// CS[s][g][i] = sum_{j in chunk g} E[i,j] (exact fp32): kills the E-quant
// mean-term in the column-split step. ES[s][i] = sum_g CS: same for rows.
__global__ __launch_bounds__(256) void k_quant(const float* __restrict__ A,
                                               const unsigned* __restrict__ smax,
                                               int* __restrict__ Epk,
                                               float* __restrict__ ES,
                                               float* __restrict__ CS) {
    __shared__ int tile[64][129];     // int8 bytes of e4 values in [-7,7]
    __shared__ float fsumC[64][4];    // per-row per-chunk exact sums
    const int s  = blockIdx.x >> 3;
    const int i0 = (blockIdx.x & 7) * 64;
    const float se  = __uint_as_float(smax[s]);
    const float inv = se > 0.0f ? 7.0f / se : 0.0f;   // int4 grid: se4 = se/7
    const float c = 1.0f / 512.0f;
    const int tl = threadIdx.x & 127;
    const int rh = threadIdx.x >> 7;
    if (threadIdx.x < 256) ((float*)fsumC)[threadIdx.x] = 0.0f;
    __syncthreads();
    for (int ro = 0; ro < 64; ro += 2) {
        const int r = ro + rh;
        const int i = i0 + r;
        float4 a4 = ((const float4*)A)[(size_t)(i * 64 + s) * 128 + tl];
        const float e0 = expf(a4.x) - c, e1 = expf(a4.y) - c;
        const float e2 = expf(a4.z) - c, e3 = expf(a4.w) - c;
        int q0 = (int)rintf(fminf(fmaxf(e0 * inv, -7.0f), 7.0f));
        int q1 = (int)rintf(fminf(fmaxf(e1 * inv, -7.0f), 7.0f));
        int q2 = (int)rintf(fminf(fmaxf(e2 * inv, -7.0f), 7.0f));
        int q3 = (int)rintf(fminf(fmaxf(e3 * inv, -7.0f), 7.0f));
        tile[r][tl] = (q0 & 255) | ((q1 & 255) << 8) | ((q2 & 255) << 16) | ((q3 & 255) << 24);
        // exact fp32 per-chunk rowsum: 32-lane group = one 128-col chunk
        float gs = e0 + e1 + e2 + e3;
        #pragma unroll
        for (int o = 16; o > 0; o >>= 1) gs += __shfl_xor(gs, o, 64);
        if ((threadIdx.x & 31) == 0) atomicAdd(&fsumC[r][tl >> 5], gs);
    }
    __syncthreads();
    if (threadIdx.x < 256) {
        const int r = threadIdx.x >> 2, gg = threadIdx.x & 3;
        CS[((size_t)(s * GS + gg) << 9) + i0 + r] = fsumC[r][gg];
    }
    if (threadIdx.x < 64) {
        const int r = threadIdx.x;
        ES[(s << 9) + i0 + r] = (fsumC[r][0] + fsumC[r][1]) + (fsumC[r][2] + fsumC[r][3]);
    }
    // pack nibble pairs (col j with col j+16 of the same 32-block) and write
    const int il = threadIdx.x & 63;
    const int jg = threadIdx.x >> 6;          // 0..3
    for (int jo = 0; jo < 4; ++jo) {
        const int j32 = jg * 4 + jo;
        int4 v;
        v.x = (tile[il][8 * j32 + 0] & 0x0F0F0F0F) | ((tile[il][8 * j32 + 4] & 0x0F0F0F0F) << 4);
        v.y = (tile[il][8 * j32 + 1] & 0x0F0F0F0F) | ((tile[il][8 * j32 + 5] & 0x0F0F0F0F) << 4);
        v.z = (tile[il][8 * j32 + 2] & 0x0F0F0F0F) | ((tile[il][8 * j32 + 6] & 0x0F0F0F0F) << 4);
        v.w = (tile[il][8 * j32 + 3] & 0x0F0F0F0F) | ((tile[il][8 * j32 + 7] & 0x0F0F0F0F) << 4);
        ((int4*)Epk)[((size_t)(s * 16 + j32) * 512) + i0 + il] = v;
    }
}

// ---- Main kernel: 2 matvec steps per ONE exchange (super-step) ----
// Super-step k handles symbols s_R = xs[2k] (ROW-split: block g computes its
// 128 rows of alpha_{2k+1}, keeps them LOCAL in fp32) and s_C = xs[2k+1]
// (COLUMN-split: block g quantizes its own chunk of alpha_{2k+1} against the
// known global mean mu_{2k} and computes the full-512-row partial y_g; the
// partials are summed by the consumers). Only y is exchanged -> exchange
// hops halved vs round 4. Transport: LLC tagged words, tag = k+1, '>='
// compare + memset (round-4 proven). Producer lead bounded to 1 super-step
// (publish k+2 requires own gather of k+1, requires all siblings' publish of
// k+1, requires their gather of k) -> parity double-buffer is overwrite-safe.
// 256 blocks x 1024 thr co-resident => polls cannot deadlock.
__global__ __launch_bounds__(1024) void k_fsa(const int* __restrict__ Epk,
                                              const float* __restrict__ ES,
                                              const float* __restrict__ CS,
                                              const unsigned* __restrict__ smax,
                                              const float* __restrict__ init_w,
                                              const float* __restrict__ fin_w,
                                              const int* __restrict__ xs,
                                              ull* __restrict__ ax,   // [2][BN][GS][QN] tagged y
                                              float* __restrict__ out) {
    __shared__ __align__(16) int qa[2][QN / 4];    // int8 alpha (full), parity
    __shared__ __align__(16) int qloc[QN / 16];    // int8 chunk quant (128 B)
    __shared__ int   xs_l[TN];
    __shared__ float wsum[8];                      // sync-wave partials (m)
    __shared__ float sws[8];                       // compute-wave partials (S_g)
    __shared__ float se_l[SN];
    __shared__ float mb[2];                        // block sum m, parity

    const int t    = threadIdx.x;
    const int b    = blockIdx.x & (BN - 1);   // blockIdx = g*64 + b
    const int g    = blockIdx.x >> 6;
    const int lane = t & 63, wave = t >> 6;
    const int tr   = t & 3;                   // phase R: col chunk
    const int lr   = t >> 2;                  // phase R: local row 0..127
    const int irow = (g << 7) + lr;           // phase R: owned output row
    const int u    = t - 512;                 // sync: owned alpha index

    if (t < TN) xs_l[t] = xs[b * TN + t];
    if (t < SN) se_l[t] = __uint_as_float(smax[t]) * (0.125f / 889.0f); // Kq/(127*7)

    const float c  = 1.0f / 512.0f;
    const float Kq = 0.125f;

    const int4* __restrict__ Epb = (const int4*)Epk;
    int4 eR[4], eC[4];
    float ESv = 0.0f, CSv = 0.0f;
    float av = 0.0f;   // sync: gathered alpha value

    if (t < 512) {
        // prefetch both phases of super-step 0 (symbols straight from global)
        const int s0 = xs[b * TN], s1 = xs[b * TN + 1];
        const int4* EpR = Epb + (size_t)(s0 * 16 + tr * 4) * 512 + irow;
        const int4* EpC = Epb + (size_t)(s1 * 16 + g * 4) * 512 + t;
        #pragma unroll
        for (int k = 0; k < 4; ++k) { eR[k] = EpR[(size_t)k * 512]; eC[k] = EpC[(size_t)k * 512]; }
        if (tr == 0) ESv = ES[(s0 << 9) + irow];
        CSv = CS[((size_t)(s1 * GS + g) << 9) + t];
    } else {
        // initial alpha: one element per sync thread, computed redundantly
        av = expf(init_w[u]);
        float ws = wave_sum(av);
        if (lane == 0) wsum[wave - 8] = ws;
    }
    barrier_lds();
    if (t >= 512) {
        float m0 = 0.0f;
        #pragma unroll
        for (int w = 0; w < 8; ++w) m0 += wsum[w];
        const float mu     = m0 * (1.0f / 512.0f);
        const float inv_sa = 127.0f / (Kq * mu);
        const int q = (int)rintf(fminf(fmaxf((av - mu) * inv_sa, -127.0f), 127.0f));
        ((char*)qa)[u] = (char)q;             // parity-0 buffer, byte u
        if (u == 0) mb[0] = m0;
    }
    barrier_lds();

    for (int k = 0; k < TN / 2; ++k) {
        const int par = k & 1;
        float mu = 0.0f;
        if (t < 512) {
            const int sR  = xs_l[2 * k];
            const int sRn = xs_l[(2 * k + 2) & (TN - 1)];   // wraps: dummy at end
            const float mm = mb[par];
            mu = mm * (1.0f / 512.0f);
            // ---- phase R: rows [128g,128g+128) of alpha_{2k+1} ----
            const int4* qp   = (const int4*)qa[par];
            const int4* EpRn = Epb + (size_t)(sRn * 16 + tr * 4) * 512 + irow;
            int a0 = 0, a1 = 0, a2 = 0, a3 = 0;
            #pragma unroll
            for (int k4 = 0; k4 < 4; ++k4) {
                const int4 E4 = eR[k4];
                eR[k4] = EpRn[(size_t)k4 * 512];
                const int4 qlo = qp[2 * (4 * tr + k4) + 0];
                const int4 qhi = qp[2 * (4 * tr + k4) + 1];
                a0 = SDOT4(NIB_LO(E4.x), qlo.x, a0);
                a1 = SDOT4(NIB_HI(E4.x), qhi.x, a1);
                a2 = SDOT4(NIB_LO(E4.y), qlo.y, a2);
                a3 = SDOT4(NIB_HI(E4.y), qhi.y, a3);
                a0 = SDOT4(NIB_LO(E4.z), qlo.z, a0);
                a1 = SDOT4(NIB_HI(E4.z), qhi.z, a1);
                a2 = SDOT4(NIB_LO(E4.w), qlo.w, a2);
                a3 = SDOT4(NIB_HI(E4.w), qhi.w, a3);
            }
            __builtin_amdgcn_sched_barrier(0);   // pin eR re-issue before the rest
            int acc = (a0 + a1) + (a2 + a3);
            acc += __shfl_xor(acc, 1, 64);       // reduce over tr (lane bits 0..1)
            acc += __shfl_xor(acc, 2, 64);
            float outv = 0.0f;
            if (tr == 0) {
                outv = c * mm + mu * (ESv + se_l[sR] * (float)acc);
                ESv = ES[(sRn << 9) + irow];     // prefetch next ES
                // quantize own chunk vs mu_{2k} (deviation ~0.2% mu << Kq=12.5%)
                const float inv_sa = 127.0f / (Kq * mu);
                const int q8 = (int)rintf(fminf(fmaxf((outv - mu) * inv_sa, -127.0f), 127.0f));
                ((char*)qloc)[lr] = (char)q8;
            }
            float ws = wave_sum(outv);           // S_g partial (non-tr0 lanes add 0)
            if (lane == 0) sws[wave] = ws;
        }
        barrier_lds();   // A: qloc + sws visible (intra-block only -- no exchange!)

        if (t < 512) {
            const int sC  = xs_l[2 * k + 1];
            const int sCn = xs_l[(2 * k + 3) & (TN - 1)];
            float Sg = 0.0f;
            #pragma unroll
            for (int w = 0; w < 8; ++w) Sg += sws[w];
            // ---- phase C: full-512-row partial over column chunk g ----
            const int4* qc   = (const int4*)qloc;
            const int4* EpCn = Epb + (size_t)(sCn * 16 + g * 4) * 512 + t;
            int a0 = 0, a1 = 0, a2 = 0, a3 = 0;
            #pragma unroll
            for (int k4 = 0; k4 < 4; ++k4) {
                const int4 E4 = eC[k4];
                eC[k4] = EpCn[(size_t)k4 * 512];
                const int4 ql = qc[2 * k4 + 0];   // local cols 32k4+4w+{0..3}
                const int4 qh = qc[2 * k4 + 1];   // local cols 32k4+16+4w+{0..3}
                a0 = SDOT4(NIB_LO(E4.x), ql.x, a0);
                a1 = SDOT4(NIB_HI(E4.x), qh.x, a1);
                a2 = SDOT4(NIB_LO(E4.y), ql.y, a2);
                a3 = SDOT4(NIB_HI(E4.y), qh.y, a3);
                a0 = SDOT4(NIB_LO(E4.z), ql.z, a0);
                a1 = SDOT4(NIB_HI(E4.z), qh.z, a1);
                a2 = SDOT4(NIB_LO(E4.w), ql.w, a2);
                a3 = SDOT4(NIB_HI(E4.w), qh.w, a3);
            }
            __builtin_amdgcn_sched_barrier(0);
            const int accC = (a0 + a1) + (a2 + a3);
            // y_g[i] = c*S_g + mu*(CS_g[i] + se*acc)  (exact mean terms)
            const float y = c * Sg + mu * (CSv + se_l[sC] * (float)accC);
            CSv = CS[((size_t)(sCn * GS + g) << 9) + t];   // prefetch next CS
            st_tag(ax + ((size_t)((par ^ 1) * BN + b) * GS + g) * QN + t,
                   ((ull)(unsigned)(k + 1) << 32) | (ull)__float_as_uint(y));
        } else {
            // gather: poll the 4 sibling partials for own row u, sum them
            const unsigned want = (unsigned)(k + 1);
            const ull* ap = ax + (size_t)((par ^ 1) * BN + b) * GS * QN + u;
            ull w0 = ld_tag(ap + 0 * QN);
            ull w1 = ld_tag(ap + 1 * QN);
            ull w2 = ld_tag(ap + 2 * QN);
            ull w3 = ld_tag(ap + 3 * QN);
            int gd = 0;
            while ((((unsigned)(w0 >> 32) < want) | ((unsigned)(w1 >> 32) < want) |
                    ((unsigned)(w2 >> 32) < want) | ((unsigned)(w3 >> 32) < want)) &&
                   ++gd < POLL_GUARD) {
                __builtin_amdgcn_s_sleep(1);
                w0 = ld_tag(ap + 0 * QN);
                w1 = ld_tag(ap + 1 * QN);
                w2 = ld_tag(ap + 2 * QN);
                w3 = ld_tag(ap + 3 * QN);
            }
            // fixed order -> bitwise identical across all blocks
            av = (__uint_as_float((unsigned)w0) + __uint_as_float((unsigned)w1)) +
                 (__uint_as_float((unsigned)w2) + __uint_as_float((unsigned)w3));
            float ws = wave_sum(av);
            if (lane == 0) wsum[wave - 8] = ws;
        }
        barrier_lds();   // 1: wsum visible

        if (t >= 512) {
            float m = 0.0f;
            #pragma unroll
            for (int w = 0; w < 8; ++w) m += wsum[w];    // same tree in all blocks
            const float mu2    = m * (1.0f / 512.0f);
            const float inv_sa = 127.0f / (Kq * mu2);
            const int q = (int)rintf(fminf(fmaxf((av - mu2) * inv_sa, -127.0f), 127.0f));
            ((char*)qa)[(par ^ 1) * QN + u] = (char)q;
            if (u == 0) mb[par ^ 1] = m;
        }
        barrier_lds();   // 2: qa[par^1] + mb[par^1] ready for next super-step
    }

    // finalize: sync threads hold gathered final alpha (tag 128) in av
    {
        float v = 0.0f;
        if (t >= 512) {
            v = av * expf(fin_w[u]);
            float ws = wave_sum(v);
            if (lane == 0) wsum[wave - 8] = ws;
        }
        barrier_lds();
        if (g == 0 && t == 512) {
            float tot = 0.0f;
            #pragma unroll
            for (int w = 0; w < 8; ++w) tot += wsum[w];
            out[b] = logf(tot);
        }
    }
}

extern "C" void kernel_launch(void* const* d_in, const int* in_sizes, int n_in,
                              void* d_out, int out_size, void* d_ws, size_t ws_size,
                              hipStream_t stream) {
    const float* A      = (const float*)d_in[0];   // (Q, S, Q) fp32 log-weights
    const float* init_w = (const float*)d_in[1];   // (Q,)
    const float* fin_w  = (const float*)d_in[2];   // (Q,)
    const int*   xs     = (const int*)d_in[3];     // (B, T) int32
    float* out = (float*)d_out;                    // (B,) fp32

    char* ws = (char*)d_ws;
    int*      Epk  = (int*)ws;                                         // 8 MiB (int4 nibbles)
    float*    ES   = (float*)(ws + (8u << 20));                        // 128 KiB
    float*    CS   = (float*)(ws + (8u << 20) + (128u << 10));         // 512 KiB
    unsigned* smax = (unsigned*)(ws + (8u << 20) + (640u << 10));      // 1 KiB slot
    ull*      ax   = (ull*)(ws + (8u << 20) + (641u << 10));           // 2 MiB

    // tags reset every launch (round-4 proven protocol: LLC write-through
    // transport + memset + 'tag >= want' equality-free compare)
    hipMemsetAsync(smax, 0, (1u << 10) + (2u << 20), stream);
    k_minmax<<<512, 256, 0, stream>>>(A, smax);
    k_quant<<<512, 256, 0, stream>>>(A, smax, Epk, ES, CS);
    k_fsa<<<GS * BN, 1024, 0, stream>>>(Epk, ES, CS, smax, init_w, fin_w, xs, ax, out);
}